// Round 9
// baseline (353.264 us; speedup 1.0000x reference)
//
#include <hip/hip_runtime.h>
#include <hip/hip_bf16.h>
#include <cstdint>

typedef __attribute__((ext_vector_type(8))) short bf16x8;
typedef __attribute__((ext_vector_type(4))) float f32x4;
typedef __attribute__((ext_vector_type(8))) unsigned short u16x8;
typedef __attribute__((ext_vector_type(4))) unsigned int u32x4;

__device__ __forceinline__ unsigned short f2bf(float f) {
    unsigned int u = __float_as_uint(f);
    unsigned int r = (u + 0x7fffu + ((u >> 16) & 1u)) >> 16;
    return (unsigned short)r;
}

__device__ __forceinline__ float tanh_fast(float x) {
    return 1.0f - 2.0f / (__expf(2.0f * x) + 1.0f);
}

#define GLDS(SRC, DST) __builtin_amdgcn_global_load_lds(                         \
        (const __attribute__((address_space(1))) void*)(SRC),                    \
        (__attribute__((address_space(3))) void*)(DST), 16, 0, 0)

// ---------- K0: w_v -> bf16 fragment-tiled B (per head) ----------
// out[h][kt][chunk c=cb*64+kg*16+cc][8]; col e=h*128+cb*16+cc, k(f)=kt*32+kg*8..+8
__global__ __launch_bounds__(256) void wv_tile_kernel(
        const float* __restrict__ wv, unsigned short* __restrict__ out) {
    __shared__ float tile[32][129];
    const int h = blockIdx.x;    // 0..7
    const int kt = blockIdx.y;   // 0..31
    const int t = threadIdx.x;
    for (int i = t; i < 1024; i += 256) {
        const int fl = i >> 5;
        const int e4 = (i & 31) * 4;
        const float4 v = *reinterpret_cast<const float4*>(
            wv + (size_t)(kt * 32 + fl) * 1024 + h * 128 + e4);
        tile[fl][e4 + 0] = v.x; tile[fl][e4 + 1] = v.y;
        tile[fl][e4 + 2] = v.z; tile[fl][e4 + 3] = v.w;
    }
    __syncthreads();
#pragma unroll
    for (int cc2 = 0; cc2 < 2; ++cc2) {
        const int c = cc2 * 256 + t;
        const int cb = c >> 6, kg = (c >> 4) & 3, ccl = c & 15;
        const int e_local = cb * 16 + ccl;
        u16x8 u;
#pragma unroll
        for (int jj = 0; jj < 8; ++jj) u[jj] = f2bf(tile[kg * 8 + jj][e_local]);
        *reinterpret_cast<u16x8*>(out + (((size_t)h * 32 + kt) * 512 + c) * 8) = u;
    }
}

// ---------- K1: q projection ----------
__global__ __launch_bounds__(128) void qproj_kernel(
        const float* __restrict__ query, const float* __restrict__ w_q,
        float* __restrict__ ws_q) {
    __shared__ float qs[1024];
    int bh = blockIdx.x;
    int b = bh >> 3, h = bh & 7;
    int t = threadIdx.x;
    for (int i = t; i < 1024; i += 128) qs[i] = query[(size_t)b * 1024 + i];
    __syncthreads();
    float acc = 0.f;
    const float* wcol = w_q + h * 128 + t;
    for (int f = 0; f < 1024; ++f) acc += qs[f] * wcol[(size_t)f * 1024];
    ws_q[(size_t)bh * 128 + t] = acc;
}

// ---------- K2: conv1d location features ----------
__global__ __launch_bounds__(256) void loc_conv_kernel(
        const float* __restrict__ pa, const float* __restrict__ conv_w,
        const float* __restrict__ conv_b, float* __restrict__ ws_loc) {
    __shared__ float pas[8][258];
    __shared__ float cw[240];
    __shared__ float cb[16];
    int b = blockIdx.x, k0 = blockIdx.y * 256;
    int t = threadIdx.x;
    for (int i = t; i < 8 * 258; i += 256) {
        int hh = i / 258, kk = i % 258;
        int gk = k0 + kk - 1;
        pas[hh][kk] = (gk >= 0 && gk < 4096) ? pa[((size_t)(b * 8 + hh)) * 4096 + gk] : 0.f;
    }
    if (t < 240) cw[t] = conv_w[t];
    if (t < 10) cb[t] = conv_b[t];
    __syncthreads();
#pragma unroll
    for (int c = 0; c < 10; ++c) {
        float acc = cb[c];
#pragma unroll
        for (int hh = 0; hh < 8; ++hh) {
            acc += pas[hh][t] * cw[(c * 8 + hh) * 3 + 0]
                 + pas[hh][t + 1] * cw[(c * 8 + hh) * 3 + 1]
                 + pas[hh][t + 2] * cw[(c * 8 + hh) * 3 + 2];
        }
        ws_loc[((size_t)(b * 10 + c)) * 4096 + k0 + t] = acc;
    }
}

// ---------- K2b: le[b,k,d] = tanh(sum_c loc[b,c,k]*w_u[c,d]) ----------
__global__ __launch_bounds__(256) void loc_energy_kernel(
        const float* __restrict__ ws_loc, const float* __restrict__ w_u,
        float* __restrict__ le) {
    __shared__ float loc_s[10][128];
    __shared__ float wu_s[10][128];
    const int b = blockIdx.x, k0 = blockIdx.y * 128;
    const int t = threadIdx.x;
    for (int i = t; i < 1280; i += 256) {
        const int c = i >> 7, r = i & 127;
        loc_s[c][r] = ws_loc[((size_t)(b * 10 + c)) * 4096 + k0 + r];
        wu_s[c][r] = w_u[i];
    }
    __syncthreads();
    const int k = t >> 1;
    const int d0 = (t & 1) * 64;
    float lc[10];
#pragma unroll
    for (int c = 0; c < 10; ++c) lc[c] = loc_s[c][k];
    float* dst = le + ((size_t)(b * 4096) + k0 + k) * 128 + d0;
#pragma unroll
    for (int dd = 0; dd < 64; dd += 4) {
        float4 o;
#pragma unroll
        for (int jj = 0; jj < 4; ++jj) {
            float s = 0.f;
#pragma unroll
            for (int c = 0; c < 10; ++c) s += lc[c] * wu_s[c][d0 + dd + jj];
            ((float*)&o)[jj] = tanh_fast(s);
        }
        *reinterpret_cast<float4*>(dst + dd) = o;
    }
}

// ---------- K3: fused bf16 MFMA GEMM + energy + score ----------
// BM=128 rows, BN=256 (2 heads), BK=32; 512 thr, 8 waves (2M x 4N), wave C=64x64.
// A: fp32 -> regs (2 iters ahead) -> v_cvt_pk_bf16 -> ds_write_b128, thread t owns
//    chunk t (consecutive lanes -> consecutive 16B -> conflict-free).
// B: pre-tiled bf16 via global_load_lds (2 per thread per kt).
#define NT 32
__global__ __launch_bounds__(512) void gemm_score_kernel(
        const float* __restrict__ key_in, const unsigned short* __restrict__ wvT_tiled,
        const float* __restrict__ le,
        const float* __restrict__ ws_q, const float* __restrict__ bias,
        const float* __restrict__ score_w, const float* __restrict__ score_b,
        float* __restrict__ align_out) {
    __shared__ __align__(16) unsigned short As[2][4096];    // 16 KB
    __shared__ __align__(16) unsigned short Bs[2][8192];    // 32 KB
    __shared__ float qb_sm[256], sw_sm[128];
    __shared__ float partial[128][4];

    const int t = threadIdx.x;
    const int lane = t & 63, wid = t >> 6;
    const int wm = wid >> 2;          // 0..1 : M-half
    const int wn = wid & 3;           // 0..3 : (head, d-half)

    // XCD swizzle: the 4 head-pair blocks of one panel adjacent on one XCD
    const int fid = blockIdx.x;       // 0..2047
    const int x = fid & 7, j = fid >> 3;     // j: 0..255
    const int bm = x * 64 + (j >> 2);        // panel 0..511 (128 rows)
    const int hp = j & 3;                    // head-pair 0..3
    const int b = bm >> 5;
    const int kk0 = (bm & 31) << 7;

    if (t < 256) {
        const int hh = t >> 7, d = t & 127;
        qb_sm[t] = ws_q[(size_t)(b * 8 + hp * 2 + hh) * 128 + d] + bias[d];
        if (t < 128) sw_sm[t] = score_w[t];
    }

    // ---- A staging: thread t owns chunk t: row=(t>>6)*16+(t&15), kseg=(t>>4)&3 ----
    const int rowA = (t >> 6) * 16 + (t & 15);
    const int ksA = (t >> 4) & 3;
    const float* aRow = key_in + ((size_t)(b * 4096 + kk0) + rowA) * 1024 + ksA * 8;
    const int dst0 = t * 8;                                        // ushort idx (16B/lane)

    // ---- B staging: thread stages two 16B chunks of one head ----
    const unsigned short* bT = wvT_tiled
        + (size_t)(hp * 2 + (t >> 8)) * 131072 + (t & 255) * 8;
    const int dstB = (t >> 8) * 4096 + (t & 255) * 8;              // ushort idx

    float4 st0, st1;

#define LOADA(KT) {                                                               \
        const float* p_ = aRow + (KT) * 32;                                       \
        st0 = *reinterpret_cast<const float4*>(p_);                               \
        st1 = *reinterpret_cast<const float4*>(p_ + 4); }

#define WRITEA(BUF) {                                                             \
        __hip_bfloat162 h0_ = __float22bfloat162_rn({st0.x, st0.y});              \
        __hip_bfloat162 h1_ = __float22bfloat162_rn({st0.z, st0.w});              \
        __hip_bfloat162 h2_ = __float22bfloat162_rn({st1.x, st1.y});              \
        __hip_bfloat162 h3_ = __float22bfloat162_rn({st1.z, st1.w});              \
        u32x4 u_;                                                                 \
        u_[0] = *reinterpret_cast<unsigned int*>(&h0_);                           \
        u_[1] = *reinterpret_cast<unsigned int*>(&h1_);                           \
        u_[2] = *reinterpret_cast<unsigned int*>(&h2_);                           \
        u_[3] = *reinterpret_cast<unsigned int*>(&h3_);                           \
        *reinterpret_cast<u32x4*>(&As[BUF][dst0]) = u_; }

#define STAGE_B(BUF, KT) {                                                        \
        GLDS(bT + (size_t)(KT) * 4096, &Bs[BUF][dstB]);                           \
        GLDS(bT + (size_t)(KT) * 4096 + 2048, &Bs[BUF][dstB + 2048]); }

    f32x4 acc[4][4] = {};

    // prologue
    LOADA(0);
    STAGE_B(0, 0);
    WRITEA(0);
    LOADA(1);
    __syncthreads();

    for (int kt = 0; kt < NT; ++kt) {
        const int cur = kt & 1;
        if (kt < NT - 1) {
            STAGE_B(cur ^ 1, kt + 1);
            WRITEA(cur ^ 1);            // regs loaded last iteration
        }
        if (kt < NT - 2) LOADA(kt + 2); // issue early, lands under MFMA
        bf16x8 af[4], bg[4];
#pragma unroll
        for (int mf = 0; mf < 4; ++mf)
            af[mf] = *reinterpret_cast<const bf16x8*>(&As[cur][(wm * 4 + mf) * 512 + lane * 8]);
#pragma unroll
        for (int nf = 0; nf < 4; ++nf)
            bg[nf] = *reinterpret_cast<const bf16x8*>(
                &Bs[cur][(wn >> 1) * 4096 + ((wn & 1) * 4 + nf) * 512 + lane * 8]);
#pragma unroll
        for (int mf = 0; mf < 4; ++mf)
#pragma unroll
            for (int nf = 0; nf < 4; ++nf)
                acc[mf][nf] = __builtin_amdgcn_mfma_f32_16x16x32_bf16(
                    af[mf], bg[nf], acc[mf][nf], 0, 0, 0);
        __syncthreads();
    }

    // ---- epilogue: score = sum_d tanh(kproj + q + bias + le) * sw ----
    const float K2 = 2.8853900817779268f;
    const float sb = score_b[0];
    const int g = lane >> 4;
    float kqb[4], swv[4];
#pragma unroll
    for (int nf = 0; nf < 4; ++nf) {
        const int d128 = (wn & 1) * 64 + nf * 16 + (lane & 15);
        kqb[nf] = qb_sm[(wn >> 1) * 128 + d128] * K2;
        swv[nf] = sw_sm[d128];
    }
    const float* leB = le + ((size_t)(b * 4096 + kk0) + wm * 64 + g * 4) * 128
                       + (wn & 1) * 64 + (lane & 15);

#pragma unroll
    for (int mf = 0; mf < 4; ++mf) {
        float lv[16];
#pragma unroll
        for (int jj = 0; jj < 4; ++jj)
#pragma unroll
            for (int nf = 0; nf < 4; ++nf)
                lv[jj * 4 + nf] = leB[(size_t)(mf * 16 + jj) * 128 + nf * 16];
#pragma unroll
        for (int jj = 0; jj < 4; ++jj) {
            const int row_l = wm * 64 + mf * 16 + g * 4 + jj;
            float sum = 0.f;
#pragma unroll
            for (int nf = 0; nf < 4; ++nf) {
                const float m = fmaf(K2, lv[jj * 4 + nf], kqb[nf]);
                const float tt = fmaf(K2, acc[mf][nf][jj], m);
                const float y = __builtin_amdgcn_exp2f(tt);
                const float r = fmaf(-2.0f, __builtin_amdgcn_rcpf(y + 1.0f), 1.0f);
                sum = fmaf(r, swv[nf], sum);
            }
            sum += __shfl_xor(sum, 1);
            sum += __shfl_xor(sum, 2);
            sum += __shfl_xor(sum, 4);
            sum += __shfl_xor(sum, 8);
            if ((lane & 15) == 0) partial[row_l][wn] = sum;
        }
    }
    __syncthreads();
    if (t < 256) {
        const int r = t >> 1, hh = t & 1;
        const float sc = partial[r][hh * 2] + partial[r][hh * 2 + 1] + sb;
        align_out[(size_t)(b * 8 + hp * 2 + hh) * 4096 + kk0 + r] = sc;
    }
}

// ---------- K4: softmax over k ----------
__global__ __launch_bounds__(256) void softmax_kernel(float* __restrict__ align_o) {
    const int bh = blockIdx.x;
    float* row = align_o + (size_t)bh * 4096;
    const int t = threadIdx.x;
    float v[16];
    float m = -1e30f;
#pragma unroll
    for (int i = 0; i < 16; ++i) {
        v[i] = row[i * 256 + t];
        m = fmaxf(m, v[i]);
    }
#pragma unroll
    for (int off = 32; off; off >>= 1) m = fmaxf(m, __shfl_xor(m, off));
    __shared__ float sm[4], ss[4];
    const int wid = t >> 6;
    if ((t & 63) == 0) sm[wid] = m;
    __syncthreads();
    m = fmaxf(fmaxf(sm[0], sm[1]), fmaxf(sm[2], sm[3]));
    float s = 0.f;
#pragma unroll
    for (int i = 0; i < 16; ++i) {
        v[i] = __expf(v[i] - m);
        s += v[i];
    }
#pragma unroll
    for (int off = 32; off; off >>= 1) s += __shfl_xor(s, off);
    if ((t & 63) == 0) ss[wid] = s;
    __syncthreads();
    s = ss[0] + ss[1] + ss[2] + ss[3];
    const float inv = 1.f / s;
#pragma unroll
    for (int i = 0; i < 16; ++i) row[i * 256 + t] = v[i] * inv;
}

// ---------- K5: split-K context partials (float4) ----------
__global__ __launch_bounds__(256) void ctx_partial_kernel(
        const float* __restrict__ value, const float* __restrict__ align_o,
        float* __restrict__ pctx) {
    const int s = blockIdx.x;    // 0..31
    const int bh = blockIdx.y;   // 0..127
    const int b = bh >> 3, h = bh & 7;
    const int t = threadIdx.x;
    const int d4 = (t & 31) * 4;
    const int kg = t >> 5;
    const float* arow = align_o + (size_t)bh * 4096 + s * 128;
    const float* vbase = value + ((size_t)(b * 4096 + s * 128)) * 1024 + h * 128 + d4;
    float4 acc = {0.f, 0.f, 0.f, 0.f};
    for (int i = 0; i < 16; ++i) {
        const int kk = i * 8 + kg;
        const float a = arow[kk];
        const float4 v = *reinterpret_cast<const float4*>(vbase + (size_t)kk * 1024);
        acc.x += a * v.x; acc.y += a * v.y; acc.z += a * v.z; acc.w += a * v.w;
    }
    __shared__ float sm2[8][128];
    *reinterpret_cast<float4*>(&sm2[kg][d4]) = acc;
    __syncthreads();
    if (t < 128) {
        float s0 = 0.f;
#pragma unroll
        for (int gg = 0; gg < 8; ++gg) s0 += sm2[gg][t];
        pctx[((size_t)bh * 32 + s) * 128 + t] = s0;
    }
}

// ---------- K6: reduce context partials ----------
__global__ __launch_bounds__(128) void ctx_reduce_kernel(
        const float* __restrict__ pctx, float* __restrict__ out) {
    const int bh = blockIdx.x;
    const int t = threadIdx.x;
    float acc = 0.f;
    for (int s2 = 0; s2 < 32; ++s2) acc += pctx[((size_t)bh * 32 + s2) * 128 + t];
    out[(size_t)bh * 128 + t] = acc;
}

extern "C" void kernel_launch(void* const* d_in, const int* in_sizes, int n_in,
                              void* d_out, int out_size, void* d_ws, size_t ws_size,
                              hipStream_t stream) {
    const float* query   = (const float*)d_in[0];
    const float* key_in  = (const float*)d_in[1];
    const float* value   = (const float*)d_in[2];
    const float* pa      = (const float*)d_in[3];
    const float* conv_w  = (const float*)d_in[4];
    const float* conv_b  = (const float*)d_in[5];
    const float* w_u     = (const float*)d_in[6];
    const float* w_q     = (const float*)d_in[7];
    const float* w_v     = (const float*)d_in[8];
    const float* bias    = (const float*)d_in[9];
    const float* score_w = (const float*)d_in[10];
    const float* score_b = (const float*)d_in[11];

    float* out = (float*)d_out;
    float* ctx_out = out;                 // [128,128]
    float* align_out = out + 16384;       // [16,8,4096]

    char* ws = (char*)d_ws;
    const size_t OFF_Q    = 0;                        // 64 KB
    const size_t OFF_LOC  = 65536;                    // 2.62 MB
    const size_t OFF_WVT  = OFF_LOC + 2621440;        // 2 MB (tiled bf16)
    const size_t OFF_PCTX = OFF_WVT + 2097152;        // 2 MB
    const size_t OFF_LE   = OFF_PCTX + 2097152;       // 33.55 MB

    float* ws_q            = (float*)(ws + OFF_Q);
    float* ws_loc          = (float*)(ws + OFF_LOC);
    unsigned short* ws_wvT = (unsigned short*)(ws + OFF_WVT);
    float* ws_pctx         = (float*)(ws + OFF_PCTX);
    float* ws_le           = (float*)(ws + OFF_LE);

    hipLaunchKernelGGL(wv_tile_kernel, dim3(8, 32), dim3(256), 0, stream, w_v, ws_wvT);
    hipLaunchKernelGGL(qproj_kernel, dim3(128), dim3(128), 0, stream, query, w_q, ws_q);
    hipLaunchKernelGGL(loc_conv_kernel, dim3(16, 16), dim3(256), 0, stream, pa, conv_w, conv_b, ws_loc);
    hipLaunchKernelGGL(loc_energy_kernel, dim3(16, 32), dim3(256), 0, stream, ws_loc, w_u, ws_le);
    hipLaunchKernelGGL(gemm_score_kernel, dim3(2048), dim3(512), 0, stream,
                       key_in, ws_wvT, ws_le, ws_q, bias, score_w, score_b, align_out);
    hipLaunchKernelGGL(softmax_kernel, dim3(128), dim3(256), 0, stream, align_out);
    hipLaunchKernelGGL(ctx_partial_kernel, dim3(32, 128), dim3(256), 0, stream, value, align_out, ws_pctx);
    hipLaunchKernelGGL(ctx_reduce_kernel, dim3(128), dim3(128), 0, stream, ws_pctx, ctx_out);
}

// Round 10
// 320.116 us; speedup vs baseline: 1.1036x; 1.1036x over previous
//
#include <hip/hip_runtime.h>
#include <hip/hip_bf16.h>
#include <cstdint>

typedef __attribute__((ext_vector_type(8))) short bf16x8;
typedef __attribute__((ext_vector_type(4))) float f32x4;
typedef __attribute__((ext_vector_type(8))) unsigned short u16x8;
typedef __attribute__((ext_vector_type(4))) unsigned int u32x4;

__device__ __forceinline__ unsigned short f2bf(float f) {
    unsigned int u = __float_as_uint(f);
    unsigned int r = (u + 0x7fffu + ((u >> 16) & 1u)) >> 16;
    return (unsigned short)r;
}

__device__ __forceinline__ float tanh_fast(float x) {
    return 1.0f - 2.0f / (__expf(2.0f * x) + 1.0f);
}

#define GLDS(SRC, DST) __builtin_amdgcn_global_load_lds(                         \
        (const __attribute__((address_space(1))) void*)(SRC),                    \
        (__attribute__((address_space(3))) void*)(DST), 16, 0, 0)

// ---------- K0: w_v -> bf16 fragment-tiled B (per head) ----------
__global__ __launch_bounds__(256) void wv_tile_kernel(
        const float* __restrict__ wv, unsigned short* __restrict__ out) {
    __shared__ float tile[32][129];
    const int h = blockIdx.x;    // 0..7
    const int kt = blockIdx.y;   // 0..31
    const int t = threadIdx.x;
    for (int i = t; i < 1024; i += 256) {
        const int fl = i >> 5;
        const int e4 = (i & 31) * 4;
        const float4 v = *reinterpret_cast<const float4*>(
            wv + (size_t)(kt * 32 + fl) * 1024 + h * 128 + e4);
        tile[fl][e4 + 0] = v.x; tile[fl][e4 + 1] = v.y;
        tile[fl][e4 + 2] = v.z; tile[fl][e4 + 3] = v.w;
    }
    __syncthreads();
#pragma unroll
    for (int cc2 = 0; cc2 < 2; ++cc2) {
        const int c = cc2 * 256 + t;
        const int cb = c >> 6, kg = (c >> 4) & 3, ccl = c & 15;
        const int e_local = cb * 16 + ccl;
        u16x8 u;
#pragma unroll
        for (int jj = 0; jj < 8; ++jj) u[jj] = f2bf(tile[kg * 8 + jj][e_local]);
        *reinterpret_cast<u16x8*>(out + (((size_t)h * 32 + kt) * 512 + c) * 8) = u;
    }
}

// ---------- K1: q projection ----------
__global__ __launch_bounds__(128) void qproj_kernel(
        const float* __restrict__ query, const float* __restrict__ w_q,
        float* __restrict__ ws_q) {
    __shared__ float qs[1024];
    int bh = blockIdx.x;
    int b = bh >> 3, h = bh & 7;
    int t = threadIdx.x;
    for (int i = t; i < 1024; i += 128) qs[i] = query[(size_t)b * 1024 + i];
    __syncthreads();
    float acc = 0.f;
    const float* wcol = w_q + h * 128 + t;
    for (int f = 0; f < 1024; ++f) acc += qs[f] * wcol[(size_t)f * 1024];
    ws_q[(size_t)bh * 128 + t] = acc;
}

// ---------- K2: conv1d location features ----------
__global__ __launch_bounds__(256) void loc_conv_kernel(
        const float* __restrict__ pa, const float* __restrict__ conv_w,
        const float* __restrict__ conv_b, float* __restrict__ ws_loc) {
    __shared__ float pas[8][258];
    __shared__ float cw[240];
    __shared__ float cb[16];
    int b = blockIdx.x, k0 = blockIdx.y * 256;
    int t = threadIdx.x;
    for (int i = t; i < 8 * 258; i += 256) {
        int hh = i / 258, kk = i % 258;
        int gk = k0 + kk - 1;
        pas[hh][kk] = (gk >= 0 && gk < 4096) ? pa[((size_t)(b * 8 + hh)) * 4096 + gk] : 0.f;
    }
    if (t < 240) cw[t] = conv_w[t];
    if (t < 10) cb[t] = conv_b[t];
    __syncthreads();
#pragma unroll
    for (int c = 0; c < 10; ++c) {
        float acc = cb[c];
#pragma unroll
        for (int hh = 0; hh < 8; ++hh) {
            acc += pas[hh][t] * cw[(c * 8 + hh) * 3 + 0]
                 + pas[hh][t + 1] * cw[(c * 8 + hh) * 3 + 1]
                 + pas[hh][t + 2] * cw[(c * 8 + hh) * 3 + 2];
        }
        ws_loc[((size_t)(b * 10 + c)) * 4096 + k0 + t] = acc;
    }
}

// ---------- K2b: le[b,k,d] = tanh(sum_c loc[b,c,k]*w_u[c,d]) ----------
__global__ __launch_bounds__(256) void loc_energy_kernel(
        const float* __restrict__ ws_loc, const float* __restrict__ w_u,
        float* __restrict__ le) {
    __shared__ float loc_s[10][128];
    __shared__ float wu_s[10][128];
    const int b = blockIdx.x, k0 = blockIdx.y * 128;
    const int t = threadIdx.x;
    for (int i = t; i < 1280; i += 256) {
        const int c = i >> 7, r = i & 127;
        loc_s[c][r] = ws_loc[((size_t)(b * 10 + c)) * 4096 + k0 + r];
        wu_s[c][r] = w_u[i];
    }
    __syncthreads();
    const int k = t >> 1;
    const int d0 = (t & 1) * 64;
    float lc[10];
#pragma unroll
    for (int c = 0; c < 10; ++c) lc[c] = loc_s[c][k];
    float* dst = le + ((size_t)(b * 4096) + k0 + k) * 128 + d0;
#pragma unroll
    for (int dd = 0; dd < 64; dd += 4) {
        float4 o;
#pragma unroll
        for (int jj = 0; jj < 4; ++jj) {
            float s = 0.f;
#pragma unroll
            for (int c = 0; c < 10; ++c) s += lc[c] * wu_s[c][d0 + dd + jj];
            ((float*)&o)[jj] = tanh_fast(s);
        }
        *reinterpret_cast<float4*>(dst + dd) = o;
    }
}

// ---------- K3: fused bf16 MFMA GEMM + energy + score ----------
// BM=128 rows, BN=256 (2 heads), BK=32; 512 thr, 8 waves (2M x 4N), wave C=64x64.
// A: fp32 -> regs (coalesced: 4 lanes per 128B row-window) -> cvt_pk -> ds_write
//    at XOR-swizzled chunk p = c ^ (((c>>4)&3) | (((c>>4)&1)<<2))  (conflict-free
//    for BOTH the write's lane pattern and the fragment read's lane pattern).
// B: pre-tiled bf16 via global_load_lds (2 per thread per kt).
#define NT 32
__global__ __launch_bounds__(512) void gemm_score_kernel(
        const float* __restrict__ key_in, const unsigned short* __restrict__ wvT_tiled,
        const float* __restrict__ le,
        const float* __restrict__ ws_q, const float* __restrict__ bias,
        const float* __restrict__ score_w, const float* __restrict__ score_b,
        float* __restrict__ align_out) {
    __shared__ __align__(16) unsigned short As[2][4096];    // 16 KB
    __shared__ __align__(16) unsigned short Bs[2][8192];    // 32 KB
    __shared__ float qb_sm[256], sw_sm[128];
    __shared__ float partial[128][4];

    const int t = threadIdx.x;
    const int lane = t & 63, wid = t >> 6;
    const int wm = wid >> 2;          // 0..1 : M-half
    const int wn = wid & 3;           // 0..3 : (head, d-half)

    // XCD swizzle: the 4 head-pair blocks of one panel adjacent on one XCD
    const int fid = blockIdx.x;       // 0..2047
    const int x = fid & 7, j = fid >> 3;     // j: 0..255
    const int bm = x * 64 + (j >> 2);        // panel 0..511 (128 rows)
    const int hp = j & 3;                    // head-pair 0..3
    const int b = bm >> 5;
    const int kk0 = (bm & 31) << 7;

    if (t < 256) {
        const int hh = t >> 7, d = t & 127;
        qb_sm[t] = ws_q[(size_t)(b * 8 + hp * 2 + hh) * 128 + d] + bias[d];
        if (t < 128) sw_sm[t] = score_w[t];
    }

    // ---- A staging: thread t reads row r_=t>>2, kseg ks=t&3 (coalesced 128B/4 lanes)
    const int r_ = t >> 2, ks = t & 3;
    const float* aRow = key_in + ((size_t)(b * 4096 + kk0) + r_) * 1024 + ks * 8;
    // logical chunk c = rowblk*64 + ks*16 + (r_&15); swizzled dest:
    const int cW = (t >> 6) * 64 + ks * 16 + (r_ & 15);
    const int dst0 = (cW ^ (ks | ((ks & 1) << 2))) * 8;            // ushort idx

    // fragment-read lane swizzle (same involution): kg = lane>>4
    const int kgR = lane >> 4;
    const int laneSwz = lane ^ (kgR | ((kgR & 1) << 2));

    // ---- B staging: thread stages two 16B chunks of one head ----
    const unsigned short* bT = wvT_tiled
        + (size_t)(hp * 2 + (t >> 8)) * 131072 + (t & 255) * 8;
    const int dstB = (t >> 8) * 4096 + (t & 255) * 8;              // ushort idx

    float4 st0, st1;

#define LOADA(KT) {                                                               \
        const float* p_ = aRow + (KT) * 32;                                       \
        st0 = *reinterpret_cast<const float4*>(p_);                               \
        st1 = *reinterpret_cast<const float4*>(p_ + 4); }

#define WRITEA(BUF) {                                                             \
        __hip_bfloat162 h0_ = __float22bfloat162_rn({st0.x, st0.y});              \
        __hip_bfloat162 h1_ = __float22bfloat162_rn({st0.z, st0.w});              \
        __hip_bfloat162 h2_ = __float22bfloat162_rn({st1.x, st1.y});              \
        __hip_bfloat162 h3_ = __float22bfloat162_rn({st1.z, st1.w});              \
        u32x4 u_;                                                                 \
        u_[0] = *reinterpret_cast<unsigned int*>(&h0_);                           \
        u_[1] = *reinterpret_cast<unsigned int*>(&h1_);                           \
        u_[2] = *reinterpret_cast<unsigned int*>(&h2_);                           \
        u_[3] = *reinterpret_cast<unsigned int*>(&h3_);                           \
        *reinterpret_cast<u32x4*>(&As[BUF][dst0]) = u_; }

#define STAGE_B(BUF, KT) {                                                        \
        GLDS(bT + (size_t)(KT) * 4096, &Bs[BUF][dstB]);                           \
        GLDS(bT + (size_t)(KT) * 4096 + 2048, &Bs[BUF][dstB + 2048]); }

    f32x4 acc[4][4] = {};

    // prologue
    LOADA(0);
    STAGE_B(0, 0);
    WRITEA(0);
    LOADA(1);
    __syncthreads();

    for (int kt = 0; kt < NT; ++kt) {
        const int cur = kt & 1;
        if (kt < NT - 1) {
            STAGE_B(cur ^ 1, kt + 1);
            WRITEA(cur ^ 1);            // regs loaded last iteration
        }
        if (kt < NT - 2) LOADA(kt + 2); // issue early, lands under MFMA
        bf16x8 af[4], bg[4];
#pragma unroll
        for (int mf = 0; mf < 4; ++mf)
            af[mf] = *reinterpret_cast<const bf16x8*>(
                &As[cur][((wm * 4 + mf) * 64 + laneSwz) * 8]);
#pragma unroll
        for (int nf = 0; nf < 4; ++nf)
            bg[nf] = *reinterpret_cast<const bf16x8*>(
                &Bs[cur][(wn >> 1) * 4096 + ((wn & 1) * 4 + nf) * 512 + lane * 8]);
#pragma unroll
        for (int mf = 0; mf < 4; ++mf)
#pragma unroll
            for (int nf = 0; nf < 4; ++nf)
                acc[mf][nf] = __builtin_amdgcn_mfma_f32_16x16x32_bf16(
                    af[mf], bg[nf], acc[mf][nf], 0, 0, 0);
        __syncthreads();
    }

    // ---- epilogue: score = sum_d tanh(kproj + q + bias + le) * sw ----
    const float K2 = 2.8853900817779268f;
    const float sb = score_b[0];
    const int g = lane >> 4;
    float kqb[4], swv[4];
#pragma unroll
    for (int nf = 0; nf < 4; ++nf) {
        const int d128 = (wn & 1) * 64 + nf * 16 + (lane & 15);
        kqb[nf] = qb_sm[(wn >> 1) * 128 + d128] * K2;
        swv[nf] = sw_sm[d128];
    }
    const float* leB = le + ((size_t)(b * 4096 + kk0) + wm * 64 + g * 4) * 128
                       + (wn & 1) * 64 + (lane & 15);

#pragma unroll
    for (int mf = 0; mf < 4; ++mf) {
        float lv[16];
#pragma unroll
        for (int jj = 0; jj < 4; ++jj)
#pragma unroll
            for (int nf = 0; nf < 4; ++nf)
                lv[jj * 4 + nf] = leB[(size_t)(mf * 16 + jj) * 128 + nf * 16];
#pragma unroll
        for (int jj = 0; jj < 4; ++jj) {
            const int row_l = wm * 64 + mf * 16 + g * 4 + jj;
            float sum = 0.f;
#pragma unroll
            for (int nf = 0; nf < 4; ++nf) {
                const float m = fmaf(K2, lv[jj * 4 + nf], kqb[nf]);
                const float tt = fmaf(K2, acc[mf][nf][jj], m);
                const float y = __builtin_amdgcn_exp2f(tt);
                const float r = fmaf(-2.0f, __builtin_amdgcn_rcpf(y + 1.0f), 1.0f);
                sum = fmaf(r, swv[nf], sum);
            }
            sum += __shfl_xor(sum, 1);
            sum += __shfl_xor(sum, 2);
            sum += __shfl_xor(sum, 4);
            sum += __shfl_xor(sum, 8);
            if ((lane & 15) == 0) partial[row_l][wn] = sum;
        }
    }
    __syncthreads();
    if (t < 256) {
        const int r = t >> 1, hh = t & 1;
        const float sc = partial[r][hh * 2] + partial[r][hh * 2 + 1] + sb;
        align_out[(size_t)(b * 8 + hp * 2 + hh) * 4096 + kk0 + r] = sc;
    }
}

// ---------- K4: softmax over k ----------
__global__ __launch_bounds__(256) void softmax_kernel(float* __restrict__ align_o) {
    const int bh = blockIdx.x;
    float* row = align_o + (size_t)bh * 4096;
    const int t = threadIdx.x;
    float v[16];
    float m = -1e30f;
#pragma unroll
    for (int i = 0; i < 16; ++i) {
        v[i] = row[i * 256 + t];
        m = fmaxf(m, v[i]);
    }
#pragma unroll
    for (int off = 32; off; off >>= 1) m = fmaxf(m, __shfl_xor(m, off));
    __shared__ float sm[4], ss[4];
    const int wid = t >> 6;
    if ((t & 63) == 0) sm[wid] = m;
    __syncthreads();
    m = fmaxf(fmaxf(sm[0], sm[1]), fmaxf(sm[2], sm[3]));
    float s = 0.f;
#pragma unroll
    for (int i = 0; i < 16; ++i) {
        v[i] = __expf(v[i] - m);
        s += v[i];
    }
#pragma unroll
    for (int off = 32; off; off >>= 1) s += __shfl_xor(s, off);
    if ((t & 63) == 0) ss[wid] = s;
    __syncthreads();
    s = ss[0] + ss[1] + ss[2] + ss[3];
    const float inv = 1.f / s;
#pragma unroll
    for (int i = 0; i < 16; ++i) row[i * 256 + t] = v[i] * inv;
}

// ---------- K5: split-K context partials (float4) ----------
__global__ __launch_bounds__(256) void ctx_partial_kernel(
        const float* __restrict__ value, const float* __restrict__ align_o,
        float* __restrict__ pctx) {
    const int s = blockIdx.x;    // 0..31
    const int bh = blockIdx.y;   // 0..127
    const int b = bh >> 3, h = bh & 7;
    const int t = threadIdx.x;
    const int d4 = (t & 31) * 4;
    const int kg = t >> 5;
    const float* arow = align_o + (size_t)bh * 4096 + s * 128;
    const float* vbase = value + ((size_t)(b * 4096 + s * 128)) * 1024 + h * 128 + d4;
    float4 acc = {0.f, 0.f, 0.f, 0.f};
    for (int i = 0; i < 16; ++i) {
        const int kk = i * 8 + kg;
        const float a = arow[kk];
        const float4 v = *reinterpret_cast<const float4*>(vbase + (size_t)kk * 1024);
        acc.x += a * v.x; acc.y += a * v.y; acc.z += a * v.z; acc.w += a * v.w;
    }
    __shared__ float sm2[8][128];
    *reinterpret_cast<float4*>(&sm2[kg][d4]) = acc;
    __syncthreads();
    if (t < 128) {
        float s0 = 0.f;
#pragma unroll
        for (int gg = 0; gg < 8; ++gg) s0 += sm2[gg][t];
        pctx[((size_t)bh * 32 + s) * 128 + t] = s0;
    }
}

// ---------- K6: reduce context partials ----------
__global__ __launch_bounds__(128) void ctx_reduce_kernel(
        const float* __restrict__ pctx, float* __restrict__ out) {
    const int bh = blockIdx.x;
    const int t = threadIdx.x;
    float acc = 0.f;
    for (int s2 = 0; s2 < 32; ++s2) acc += pctx[((size_t)bh * 32 + s2) * 128 + t];
    out[(size_t)bh * 128 + t] = acc;
}

extern "C" void kernel_launch(void* const* d_in, const int* in_sizes, int n_in,
                              void* d_out, int out_size, void* d_ws, size_t ws_size,
                              hipStream_t stream) {
    const float* query   = (const float*)d_in[0];
    const float* key_in  = (const float*)d_in[1];
    const float* value   = (const float*)d_in[2];
    const float* pa      = (const float*)d_in[3];
    const float* conv_w  = (const float*)d_in[4];
    const float* conv_b  = (const float*)d_in[5];
    const float* w_u     = (const float*)d_in[6];
    const float* w_q     = (const float*)d_in[7];
    const float* w_v     = (const float*)d_in[8];
    const float* bias    = (const float*)d_in[9];
    const float* score_w = (const float*)d_in[10];
    const float* score_b = (const float*)d_in[11];

    float* out = (float*)d_out;
    float* ctx_out = out;                 // [128,128]
    float* align_out = out + 16384;       // [16,8,4096]

    char* ws = (char*)d_ws;
    const size_t OFF_Q    = 0;                        // 64 KB
    const size_t OFF_LOC  = 65536;                    // 2.62 MB
    const size_t OFF_WVT  = OFF_LOC + 2621440;        // 2 MB (tiled bf16)
    const size_t OFF_PCTX = OFF_WVT + 2097152;        // 2 MB
    const size_t OFF_LE   = OFF_PCTX + 2097152;       // 33.55 MB

    float* ws_q            = (float*)(ws + OFF_Q);
    float* ws_loc          = (float*)(ws + OFF_LOC);
    unsigned short* ws_wvT = (unsigned short*)(ws + OFF_WVT);
    float* ws_pctx         = (float*)(ws + OFF_PCTX);
    float* ws_le           = (float*)(ws + OFF_LE);

    hipLaunchKernelGGL(wv_tile_kernel, dim3(8, 32), dim3(256), 0, stream, w_v, ws_wvT);
    hipLaunchKernelGGL(qproj_kernel, dim3(128), dim3(128), 0, stream, query, w_q, ws_q);
    hipLaunchKernelGGL(loc_conv_kernel, dim3(16, 16), dim3(256), 0, stream, pa, conv_w, conv_b, ws_loc);
    hipLaunchKernelGGL(loc_energy_kernel, dim3(16, 32), dim3(256), 0, stream, ws_loc, w_u, ws_le);
    hipLaunchKernelGGL(gemm_score_kernel, dim3(2048), dim3(512), 0, stream,
                       key_in, ws_wvT, ws_le, ws_q, bias, score_w, score_b, align_out);
    hipLaunchKernelGGL(softmax_kernel, dim3(128), dim3(256), 0, stream, align_out);
    hipLaunchKernelGGL(ctx_partial_kernel, dim3(32, 128), dim3(256), 0, stream, value, align_out, ws_pctx);
    hipLaunchKernelGGL(ctx_reduce_kernel, dim3(128), dim3(128), 0, stream, ws_pctx, ctx_out);
}